// Round 1
// baseline (635.160 us; speedup 1.0000x reference)
//
#include <hip/hip_runtime.h>
#include <math.h>

// GCN: h = relu(dinv * (scatter_sum(s[src] -> dst) + s) + b), s = (x@W)*dinv
// Self-loop folded into accumulator init. deg >= 1 always (self-loops).

#define TPB 256

__global__ void k_init_deg(float* __restrict__ deg, int n) {
    int i = blockIdx.x * blockDim.x + threadIdx.x;
    if (i < n) deg[i] = 1.0f;  // self-loop
}

__global__ void k_deg(const int* __restrict__ dst, float* __restrict__ deg, int E) {
    int e = blockIdx.x * blockDim.x + threadIdx.x;
    if (e < E) atomicAdd(&deg[dst[e]], 1.0f);
}

__global__ void k_dinv(float* __restrict__ deg, int n) {
    int i = blockIdx.x * blockDim.x + threadIdx.x;
    if (i < n) deg[i] = rsqrtf(deg[i]);   // in place: deg buffer becomes dinv
}

// s1[node,f] = (x[node,:] @ W1[:,f]) * dinv[node]; acc1 init = s1 (self-loop term)
__global__ void k_xw1(const float* __restrict__ x, const float* __restrict__ W1,
                      const float* __restrict__ dinv,
                      float* __restrict__ s1, float* __restrict__ acc1, int n) {
    int t = blockIdx.x * blockDim.x + threadIdx.x;
    if (t >= n * 32) return;
    int node = t >> 5, f = t & 31;
    const float* xr = x + node * 18;
    float a = 0.f;
#pragma unroll
    for (int k = 0; k < 18; ++k) a = fmaf(xr[k], W1[k * 32 + f], a);
    float v = a * dinv[node];
    s1[t] = v;
    acc1[t] = v;
}

// one thread per (edge, feature); 32 lanes cover one edge's row
__global__ void k_scatter1(const int* __restrict__ src, const int* __restrict__ dst,
                           const float* __restrict__ s1, float* __restrict__ acc1, int E) {
    int t = blockIdx.x * blockDim.x + threadIdx.x;
    if (t >= E * 32) return;
    int e = t >> 5, f = t & 31;
    int s = src[e], d = dst[e];
    atomicAdd(&acc1[d * 32 + f], s1[s * 32 + f]);
}

__global__ void k_h1(const float* __restrict__ acc1, const float* __restrict__ dinv,
                     const float* __restrict__ b1, float* __restrict__ h1, int n) {
    int t = blockIdx.x * blockDim.x + threadIdx.x;
    if (t >= n * 32) return;
    int node = t >> 5, f = t & 31;
    h1[t] = fmaxf(fmaf(dinv[node], acc1[t], b1[f]), 0.f);
}

__global__ void k_xw2(const float* __restrict__ h1, const float* __restrict__ W2,
                      const float* __restrict__ dinv,
                      float* __restrict__ s2, float* __restrict__ acc2, int n) {
    int t = blockIdx.x * blockDim.x + threadIdx.x;
    if (t >= n * 64) return;
    int node = t >> 6, f = t & 63;
    const float* hr = h1 + node * 32;
    float a = 0.f;
#pragma unroll
    for (int k = 0; k < 32; ++k) a = fmaf(hr[k], W2[k * 64 + f], a);
    float v = a * dinv[node];
    s2[t] = v;
    acc2[t] = v;
}

__global__ void k_scatter2(const int* __restrict__ src, const int* __restrict__ dst,
                           const float* __restrict__ s2, float* __restrict__ acc2, int E) {
    int t = blockIdx.x * blockDim.x + threadIdx.x;
    if (t >= E * 64) return;
    int e = t >> 6, f = t & 63;
    int s = src[e], d = dst[e];
    atomicAdd(&acc2[d * 64 + f], s2[s * 64 + f]);
}

// one wave (64 lanes) per node: relu + FC(64->2) + log_softmax
__global__ void k_out(const float* __restrict__ acc2, const float* __restrict__ dinv,
                      const float* __restrict__ b2, const float* __restrict__ Wfc,
                      const float* __restrict__ bfc, float* __restrict__ out, int n) {
    int t = blockIdx.x * blockDim.x + threadIdx.x;
    int node = t >> 6, f = t & 63;
    if (node >= n) return;
    float v = fmaxf(fmaf(dinv[node], acc2[node * 64 + f], b2[f]), 0.f);
    float l0 = v * Wfc[f * 2 + 0];
    float l1 = v * Wfc[f * 2 + 1];
#pragma unroll
    for (int off = 32; off >= 1; off >>= 1) {
        l0 += __shfl_xor(l0, off, 64);
        l1 += __shfl_xor(l1, off, 64);
    }
    if (f == 0) {
        l0 += bfc[0];
        l1 += bfc[1];
        float m = fmaxf(l0, l1);
        float lse = m + logf(expf(l0 - m) + expf(l1 - m));
        out[node * 2 + 0] = l0 - lse;
        out[node * 2 + 1] = l1 - lse;
    }
}

extern "C" void kernel_launch(void* const* d_in, const int* in_sizes, int n_in,
                              void* d_out, int out_size, void* d_ws, size_t ws_size,
                              hipStream_t stream) {
    const float* x   = (const float*)d_in[0];
    const int*   ei  = (const int*)d_in[1];
    const float* W1  = (const float*)d_in[2];
    const float* b1  = (const float*)d_in[3];
    const float* W2  = (const float*)d_in[4];
    const float* b2  = (const float*)d_in[5];
    const float* Wfc = (const float*)d_in[6];
    const float* bfc = (const float*)d_in[7];
    float* out = (float*)d_out;

    const int n = in_sizes[0] / 18;
    const int E = in_sizes[1] / 2;
    const int* src = ei;
    const int* dst = ei + E;

    // workspace layout (floats): dinv[n] | s1[n*32] | acc1[n*32] | h1[n*32] | s2[n*64] | acc2[n*64]
    float* ws   = (float*)d_ws;
    float* dinv = ws;
    float* s1   = dinv + n;
    float* acc1 = s1 + (size_t)n * 32;
    float* h1   = acc1 + (size_t)n * 32;
    float* s2   = h1 + (size_t)n * 32;
    float* acc2 = s2 + (size_t)n * 64;

    auto blocks = [](long long work) { return (int)((work + TPB - 1) / TPB); };

    k_init_deg<<<blocks(n), TPB, 0, stream>>>(dinv, n);
    k_deg<<<blocks(E), TPB, 0, stream>>>(dst, dinv, E);
    k_dinv<<<blocks(n), TPB, 0, stream>>>(dinv, n);

    k_xw1<<<blocks((long long)n * 32), TPB, 0, stream>>>(x, W1, dinv, s1, acc1, n);
    k_scatter1<<<blocks((long long)E * 32), TPB, 0, stream>>>(src, dst, s1, acc1, E);
    k_h1<<<blocks((long long)n * 32), TPB, 0, stream>>>(acc1, dinv, b1, h1, n);

    k_xw2<<<blocks((long long)n * 64), TPB, 0, stream>>>(h1, W2, dinv, s2, acc2, n);
    k_scatter2<<<blocks((long long)E * 64), TPB, 0, stream>>>(src, dst, s2, acc2, E);

    k_out<<<blocks((long long)n * 64), TPB, 0, stream>>>(acc2, dinv, b2, Wfc, bfc, out, n);
}

// Round 2
// 432.270 us; speedup vs baseline: 1.4694x; 1.4694x over previous
//
#include <hip/hip_runtime.h>
#include <math.h>

// GCN via CSR gather (no float atomics):
//   dinv[i] = rsqrt(1 + in_deg[i])           (self-loop included)
//   s = (x@W) * dinv
//   h[d] = relu(dinv[d] * (sum_{e: dst=d} s[src(e)] + s[d]) + b)
// CSR built per-call with counting sort on dst (int atomics only).

#define TPB 256

__global__ void k_zero(int* __restrict__ cnt, int n) {
    int i = blockIdx.x * blockDim.x + threadIdx.x;
    if (i < n) cnt[i] = 0;
}

__global__ void k_count(const int* __restrict__ dst, int* __restrict__ cnt, int E) {
    int e = blockIdx.x * blockDim.x + threadIdx.x;
    if (e < E) atomicAdd(&cnt[dst[e]], 1);
}

// per-block sums of cnt
__global__ void k_bsum(const int* __restrict__ cnt, int* __restrict__ bsum, int n) {
    __shared__ int sm[TPB];
    int t = threadIdx.x;
    int i = blockIdx.x * TPB + t;
    sm[t] = (i < n) ? cnt[i] : 0;
    __syncthreads();
    for (int off = TPB / 2; off > 0; off >>= 1) {
        if (t < off) sm[t] += sm[t + off];
        __syncthreads();
    }
    if (t == 0) bsum[blockIdx.x] = sm[0];
}

// single-block exclusive scan of bsum[nb] (nb ~ 391)
__global__ void k_scan_bsum(int* __restrict__ bsum, int nb) {
    __shared__ int sm[TPB];
    int t = threadIdx.x;
    int carry = 0;
    for (int base = 0; base < nb; base += TPB) {
        int i = base + t;
        int v = (i < nb) ? bsum[i] : 0;
        sm[t] = v;
        __syncthreads();
        for (int off = 1; off < TPB; off <<= 1) {
            int x = (t >= off) ? sm[t - off] : 0;
            __syncthreads();
            sm[t] += x;
            __syncthreads();
        }
        if (i < nb) bsum[i] = carry + sm[t] - v;  // exclusive
        carry += sm[TPB - 1];
        __syncthreads();
    }
}

// row_start / cursor / dinv from cnt + scanned block offsets
__global__ void k_starts(const int* __restrict__ cnt, const int* __restrict__ boff,
                         int* __restrict__ row_start, int* __restrict__ cursor,
                         float* __restrict__ dinv, int n) {
    __shared__ int sm[TPB];
    int t = threadIdx.x;
    int i = blockIdx.x * TPB + t;
    int v = (i < n) ? cnt[i] : 0;
    sm[t] = v;
    __syncthreads();
    for (int off = 1; off < TPB; off <<= 1) {
        int x = (t >= off) ? sm[t - off] : 0;
        __syncthreads();
        sm[t] += x;
        __syncthreads();
    }
    if (i < n) {
        int start = boff[blockIdx.x] + sm[t] - v;  // exclusive
        row_start[i] = start;
        cursor[i] = start;
        dinv[i] = rsqrtf(1.0f + (float)v);
    }
}

__global__ void k_fill(const int* __restrict__ src, const int* __restrict__ dst,
                       int* __restrict__ cursor, int* __restrict__ csr_src, int E) {
    int e = blockIdx.x * blockDim.x + threadIdx.x;
    if (e < E) {
        int d = dst[e];
        int p = atomicAdd(&cursor[d], 1);
        csr_src[p] = src[e];
    }
}

// s1[node,f] = (x[node,:] @ W1[:,f]) * dinv[node]
__global__ void k_xw1(const float* __restrict__ x, const float* __restrict__ W1,
                      const float* __restrict__ dinv, float* __restrict__ s1, int n) {
    int t = blockIdx.x * blockDim.x + threadIdx.x;
    if (t >= n * 32) return;
    int node = t >> 5, f = t & 31;
    const float* xr = x + node * 18;
    float a = 0.f;
#pragma unroll
    for (int k = 0; k < 18; ++k) a = fmaf(xr[k], W1[k * 32 + f], a);
    s1[t] = a * dinv[node];
}

// h1[node,f] = relu(dinv*(self + sum_in s1[src]) + b1), f in [0,32)
__global__ void k_agg1(const float* __restrict__ s1, const int* __restrict__ row_start,
                       const int* __restrict__ cnt, const int* __restrict__ csr_src,
                       const float* __restrict__ dinv, const float* __restrict__ b1,
                       float* __restrict__ h1, int n) {
    int t = blockIdx.x * blockDim.x + threadIdx.x;
    int node = t >> 5, f = t & 31;
    if (node >= n) return;
    int beg = row_start[node], num = cnt[node];
    float acc = s1[node * 32 + f];
    int i = 0;
    for (; i + 1 < num; i += 2) {
        int sa = csr_src[beg + i];
        int sb = csr_src[beg + i + 1];
        acc += s1[sa * 32 + f] + s1[sb * 32 + f];
    }
    if (i < num) acc += s1[csr_src[beg + i] * 32 + f];
    h1[node * 32 + f] = fmaxf(fmaf(dinv[node], acc, b1[f]), 0.f);
}

// s2[node,f] = (h1[node,:] @ W2[:,f]) * dinv[node]
__global__ void k_xw2(const float* __restrict__ h1, const float* __restrict__ W2,
                      const float* __restrict__ dinv, float* __restrict__ s2, int n) {
    int t = blockIdx.x * blockDim.x + threadIdx.x;
    if (t >= n * 64) return;
    int node = t >> 6, f = t & 63;
    const float* hr = h1 + node * 32;
    float a = 0.f;
#pragma unroll
    for (int k = 0; k < 32; ++k) a = fmaf(hr[k], W2[k * 64 + f], a);
    s2[t] = a * dinv[node];
}

// layer-2 aggregation fused with relu + FC(64->2) + log_softmax
// one wave (64 lanes = 64 features) per node
__global__ void k_agg2_out(const float* __restrict__ s2, const int* __restrict__ row_start,
                           const int* __restrict__ cnt, const int* __restrict__ csr_src,
                           const float* __restrict__ dinv, const float* __restrict__ b2,
                           const float* __restrict__ Wfc, const float* __restrict__ bfc,
                           float* __restrict__ out, int n) {
    int t = blockIdx.x * blockDim.x + threadIdx.x;
    int node = t >> 6, f = t & 63;
    if (node >= n) return;
    int beg = row_start[node], num = cnt[node];
    float acc = s2[node * 64 + f];
    int i = 0;
    for (; i + 1 < num; i += 2) {
        int sa = csr_src[beg + i];
        int sb = csr_src[beg + i + 1];
        acc += s2[sa * 64 + f] + s2[sb * 64 + f];
    }
    if (i < num) acc += s2[csr_src[beg + i] * 64 + f];
    float v = fmaxf(fmaf(dinv[node], acc, b2[f]), 0.f);
    float l0 = v * Wfc[f * 2 + 0];
    float l1 = v * Wfc[f * 2 + 1];
#pragma unroll
    for (int off = 32; off >= 1; off >>= 1) {
        l0 += __shfl_xor(l0, off, 64);
        l1 += __shfl_xor(l1, off, 64);
    }
    if (f == 0) {
        l0 += bfc[0];
        l1 += bfc[1];
        float m = fmaxf(l0, l1);
        float lse = m + logf(expf(l0 - m) + expf(l1 - m));
        out[node * 2 + 0] = l0 - lse;
        out[node * 2 + 1] = l1 - lse;
    }
}

extern "C" void kernel_launch(void* const* d_in, const int* in_sizes, int n_in,
                              void* d_out, int out_size, void* d_ws, size_t ws_size,
                              hipStream_t stream) {
    const float* x   = (const float*)d_in[0];
    const int*   ei  = (const int*)d_in[1];
    const float* W1  = (const float*)d_in[2];
    const float* b1  = (const float*)d_in[3];
    const float* W2  = (const float*)d_in[4];
    const float* b2  = (const float*)d_in[5];
    const float* Wfc = (const float*)d_in[6];
    const float* bfc = (const float*)d_in[7];
    float* out = (float*)d_out;

    const int n = in_sizes[0] / 18;
    const int E = in_sizes[1] / 2;
    const int* src = ei;
    const int* dst = ei + E;
    const int nb = (n + TPB - 1) / TPB;

    // workspace layout (all 4-byte elems):
    // cnt[n] | bsum[nb] | row_start[n] | cursor[n] | csr_src[E] | dinv[n] | s1[n*32] | h1[n*32] | s2[n*64]
    char* w = (char*)d_ws;
    int*   cnt       = (int*)w;                 w += (size_t)n * 4;
    int*   bsum      = (int*)w;                 w += (size_t)nb * 4;
    int*   row_start = (int*)w;                 w += (size_t)n * 4;
    int*   cursor    = (int*)w;                 w += (size_t)n * 4;
    int*   csr_src   = (int*)w;                 w += (size_t)E * 4;
    float* dinv      = (float*)w;               w += (size_t)n * 4;
    float* s1        = (float*)w;               w += (size_t)n * 32 * 4;
    float* h1        = (float*)w;               w += (size_t)n * 32 * 4;
    float* s2        = (float*)w;               w += (size_t)n * 64 * 4;

    auto blocks = [](long long work) { return (int)((work + TPB - 1) / TPB); };

    // ---- CSR build (counting sort by dst) ----
    k_zero<<<blocks(n), TPB, 0, stream>>>(cnt, n);
    k_count<<<blocks(E), TPB, 0, stream>>>(dst, cnt, E);
    k_bsum<<<nb, TPB, 0, stream>>>(cnt, bsum, n);
    k_scan_bsum<<<1, TPB, 0, stream>>>(bsum, nb);
    k_starts<<<nb, TPB, 0, stream>>>(cnt, bsum, row_start, cursor, dinv, n);
    k_fill<<<blocks(E), TPB, 0, stream>>>(src, dst, cursor, csr_src, E);

    // ---- layer 1 ----
    k_xw1<<<blocks((long long)n * 32), TPB, 0, stream>>>(x, W1, dinv, s1, n);
    k_agg1<<<blocks((long long)n * 32), TPB, 0, stream>>>(s1, row_start, cnt, csr_src, dinv, b1, h1, n);

    // ---- layer 2 + output head ----
    k_xw2<<<blocks((long long)n * 64), TPB, 0, stream>>>(h1, W2, dinv, s2, n);
    k_agg2_out<<<blocks((long long)n * 64), TPB, 0, stream>>>(s2, row_start, cnt, csr_src, dinv, b2, Wfc, bfc, out, n);
}

// Round 3
// 378.135 us; speedup vs baseline: 1.6797x; 1.1432x over previous
//
#include <hip/hip_runtime.h>
#include <math.h>

// GCN, aggregate-then-transform (aggregation is linear, commutes with @W):
//   dinv[i] = rsqrt(1 + in_deg[i])
//   u1 = x * dinv[:,None]                  (n x 18)
//   agg1[d] = u1[d] + sum_{e:dst=d} u1[src]     (n x 18)
//   u2 = relu(dinv*(agg1@W1) + b1) * dinv  (n x 32)
//   agg2[d] = u2[d] + sum_{e:dst=d} u2[src]     (n x 32)
//   v = relu(dinv*(agg2@W2) + b2)          (n x 64) -> FC(64->2) -> log_softmax
// CSR built per-call with counting sort on dst (int atomics only).

#define TPB 256

__global__ void k_zero(int* __restrict__ cnt, int n) {
    int i = blockIdx.x * blockDim.x + threadIdx.x;
    if (i < n) cnt[i] = 0;
}

__global__ void k_count(const int* __restrict__ dst, int* __restrict__ cnt, int E) {
    int e = blockIdx.x * blockDim.x + threadIdx.x;
    if (e < E) atomicAdd(&cnt[dst[e]], 1);
}

// per-block sums of cnt
__global__ void k_bsum(const int* __restrict__ cnt, int* __restrict__ bsum, int n) {
    __shared__ int sm[TPB];
    int t = threadIdx.x;
    int i = blockIdx.x * TPB + t;
    sm[t] = (i < n) ? cnt[i] : 0;
    __syncthreads();
    for (int off = TPB / 2; off > 0; off >>= 1) {
        if (t < off) sm[t] += sm[t + off];
        __syncthreads();
    }
    if (t == 0) bsum[blockIdx.x] = sm[0];
}

// single-block exclusive scan of bsum[nb]
__global__ void k_scan_bsum(int* __restrict__ bsum, int nb) {
    __shared__ int sm[TPB];
    int t = threadIdx.x;
    int carry = 0;
    for (int base = 0; base < nb; base += TPB) {
        int i = base + t;
        int v = (i < nb) ? bsum[i] : 0;
        sm[t] = v;
        __syncthreads();
        for (int off = 1; off < TPB; off <<= 1) {
            int x = (t >= off) ? sm[t - off] : 0;
            __syncthreads();
            sm[t] += x;
            __syncthreads();
        }
        if (i < nb) bsum[i] = carry + sm[t] - v;  // exclusive
        carry += sm[TPB - 1];
        __syncthreads();
    }
}

// row_start / cursor / dinv from cnt + scanned block offsets; row_start[n] = E
__global__ void k_starts(const int* __restrict__ cnt, const int* __restrict__ boff,
                         int* __restrict__ row_start, int* __restrict__ cursor,
                         float* __restrict__ dinv, int n) {
    __shared__ int sm[TPB];
    int t = threadIdx.x;
    int i = blockIdx.x * TPB + t;
    int v = (i < n) ? cnt[i] : 0;
    sm[t] = v;
    __syncthreads();
    for (int off = 1; off < TPB; off <<= 1) {
        int x = (t >= off) ? sm[t - off] : 0;
        __syncthreads();
        sm[t] += x;
        __syncthreads();
    }
    if (i < n) {
        int start = boff[blockIdx.x] + sm[t] - v;  // exclusive
        row_start[i] = start;
        cursor[i] = start;
        dinv[i] = rsqrtf(1.0f + (float)v);
        if (i == n - 1) row_start[n] = start + v;
    }
}

__global__ void k_fill(const int* __restrict__ src, const int* __restrict__ dst,
                       int* __restrict__ cursor, int* __restrict__ csr_src, int E) {
    int e = blockIdx.x * blockDim.x + threadIdx.x;
    if (e < E) {
        int d = dst[e];
        int p = atomicAdd(&cursor[d], 1);
        csr_src[p] = src[e];
    }
}

// u1 = x * dinv (n x 18)
__global__ void k_scale1(const float* __restrict__ x, const float* __restrict__ dinv,
                         float* __restrict__ u1, int n) {
    int t = blockIdx.x * blockDim.x + threadIdx.x;
    if (t >= n * 18) return;
    int node = t / 18;
    u1[t] = x[t] * dinv[node];
}

// agg1[node,f] = u1[node,f] + sum_in u1[src,f], f in [0,18)
__global__ void k_agg1(const float* __restrict__ u1, const int* __restrict__ row_start,
                       const int* __restrict__ csr_src, float* __restrict__ agg1, int n) {
    int t = blockIdx.x * blockDim.x + threadIdx.x;
    if (t >= n * 18) return;
    int node = t / 18, f = t - node * 18;
    int beg = row_start[node], end = row_start[node + 1];
    float acc = u1[t];
    int i = beg;
    for (; i + 1 < end; i += 2) {
        int sa = csr_src[i];
        int sb = csr_src[i + 1];
        acc += u1[sa * 18 + f] + u1[sb * 18 + f];
    }
    if (i < end) acc += u1[csr_src[i] * 18 + f];
    agg1[t] = acc;
}

// u2[node,f2] = relu(dinv*(agg1row @ W1[:,f2]) + b1[f2]) * dinv, f2 in [0,32)
__global__ void k_l1(const float* __restrict__ agg1, const float* __restrict__ W1,
                     const float* __restrict__ dinv, const float* __restrict__ b1,
                     float* __restrict__ u2, int n) {
    int t = blockIdx.x * blockDim.x + threadIdx.x;
    if (t >= n * 32) return;
    int node = t >> 5, f = t & 31;
    const float* ar = agg1 + node * 18;
    float a = 0.f;
#pragma unroll
    for (int k = 0; k < 18; ++k) a = fmaf(ar[k], W1[k * 32 + f], a);
    float di = dinv[node];
    u2[t] = fmaxf(fmaf(di, a, b1[f]), 0.f) * di;
}

// agg2[node,f] = u2[node,f] + sum_in u2[src,f], f in [0,32)
__global__ void k_agg2(const float* __restrict__ u2, const int* __restrict__ row_start,
                       const int* __restrict__ csr_src, float* __restrict__ agg2, int n) {
    int t = blockIdx.x * blockDim.x + threadIdx.x;
    if (t >= n * 32) return;
    int node = t >> 5, f = t & 31;
    int beg = row_start[node], end = row_start[node + 1];
    float acc = u2[t];
    int i = beg;
    for (; i + 1 < end; i += 2) {
        int sa = csr_src[i];
        int sb = csr_src[i + 1];
        acc += u2[sa * 32 + f] + u2[sb * 32 + f];
    }
    if (i < end) acc += u2[csr_src[i] * 32 + f];
    agg2[t] = acc;
}

// per node (one wave, 64 lanes = 64 features):
// v = relu(dinv*(agg2row @ W2[:,f]) + b2[f]); FC(64->2); log_softmax
__global__ void k_l2_out(const float* __restrict__ agg2, const float* __restrict__ W2,
                         const float* __restrict__ dinv, const float* __restrict__ b2,
                         const float* __restrict__ Wfc, const float* __restrict__ bfc,
                         float* __restrict__ out, int n) {
    int t = blockIdx.x * blockDim.x + threadIdx.x;
    int node = t >> 6, f = t & 63;
    if (node >= n) return;
    const float* ar = agg2 + node * 32;
    float a = 0.f;
#pragma unroll
    for (int k = 0; k < 32; ++k) a = fmaf(ar[k], W2[k * 64 + f], a);
    float v = fmaxf(fmaf(dinv[node], a, b2[f]), 0.f);
    float l0 = v * Wfc[f * 2 + 0];
    float l1 = v * Wfc[f * 2 + 1];
#pragma unroll
    for (int off = 32; off >= 1; off >>= 1) {
        l0 += __shfl_xor(l0, off, 64);
        l1 += __shfl_xor(l1, off, 64);
    }
    if (f == 0) {
        l0 += bfc[0];
        l1 += bfc[1];
        float m = fmaxf(l0, l1);
        float lse = m + logf(expf(l0 - m) + expf(l1 - m));
        out[node * 2 + 0] = l0 - lse;
        out[node * 2 + 1] = l1 - lse;
    }
}

extern "C" void kernel_launch(void* const* d_in, const int* in_sizes, int n_in,
                              void* d_out, int out_size, void* d_ws, size_t ws_size,
                              hipStream_t stream) {
    const float* x   = (const float*)d_in[0];
    const int*   ei  = (const int*)d_in[1];
    const float* W1  = (const float*)d_in[2];
    const float* b1  = (const float*)d_in[3];
    const float* W2  = (const float*)d_in[4];
    const float* b2  = (const float*)d_in[5];
    const float* Wfc = (const float*)d_in[6];
    const float* bfc = (const float*)d_in[7];
    float* out = (float*)d_out;

    const int n = in_sizes[0] / 18;
    const int E = in_sizes[1] / 2;
    const int* src = ei;
    const int* dst = ei + E;
    const int nb = (n + TPB - 1) / TPB;

    // workspace layout (4-byte elems):
    // cnt[n] | bsum[nb] | row_start[n+1] | cursor[n] | csr_src[E] | dinv[n]
    // | u1[n*18] | agg1[n*18] | u2[n*32] | agg2[n*32]
    char* w = (char*)d_ws;
    int*   cnt       = (int*)w;    w += (size_t)n * 4;
    int*   bsum      = (int*)w;    w += (size_t)nb * 4;
    int*   row_start = (int*)w;    w += (size_t)(n + 1) * 4;
    int*   cursor    = (int*)w;    w += (size_t)n * 4;
    int*   csr_src   = (int*)w;    w += (size_t)E * 4;
    float* dinv      = (float*)w;  w += (size_t)n * 4;
    float* u1        = (float*)w;  w += (size_t)n * 18 * 4;
    float* agg1      = (float*)w;  w += (size_t)n * 18 * 4;
    float* u2        = (float*)w;  w += (size_t)n * 32 * 4;
    float* agg2      = (float*)w;  w += (size_t)n * 32 * 4;

    auto blocks = [](long long work) { return (int)((work + TPB - 1) / TPB); };

    // ---- CSR build (counting sort by dst) ----
    k_zero<<<blocks(n), TPB, 0, stream>>>(cnt, n);
    k_count<<<blocks(E), TPB, 0, stream>>>(dst, cnt, E);
    k_bsum<<<nb, TPB, 0, stream>>>(cnt, bsum, n);
    k_scan_bsum<<<1, TPB, 0, stream>>>(bsum, nb);
    k_starts<<<nb, TPB, 0, stream>>>(cnt, bsum, row_start, cursor, dinv, n);
    k_fill<<<blocks(E), TPB, 0, stream>>>(src, dst, cursor, csr_src, E);

    // ---- layer 1 ----
    k_scale1<<<blocks((long long)n * 18), TPB, 0, stream>>>(x, dinv, u1, n);
    k_agg1<<<blocks((long long)n * 18), TPB, 0, stream>>>(u1, row_start, csr_src, agg1, n);
    k_l1<<<blocks((long long)n * 32), TPB, 0, stream>>>(agg1, W1, dinv, b1, u2, n);

    // ---- layer 2 + output head ----
    k_agg2<<<blocks((long long)n * 32), TPB, 0, stream>>>(u2, row_start, csr_src, agg2, n);
    k_l2_out<<<blocks((long long)n * 64), TPB, 0, stream>>>(agg2, W2, dinv, b2, Wfc, bfc, out, n);
}

// Round 4
// 288.580 us; speedup vs baseline: 2.2010x; 1.3103x over previous
//
#include <hip/hip_runtime.h>
#include <math.h>

// GCN, aggregate-then-transform, CSR built via bucketed (two-level) counting
// sort: 256-node buckets give all heavy writes 64B-line locality (R3's k_fill
// wrote 88 MB through HBM for a 5 MB payload; this structure writes ~18 MB).

#define TPB 256
#define BSH 8                 // 256 nodes per bucket
#define BNODES 256
#define MAXBUCK 512           // LDS capacity for bucket counters (n <= 131072)
#define CH 8192               // edges per partition block

__global__ void k_zero(int* __restrict__ p, int n) {
    int i = blockIdx.x * blockDim.x + threadIdx.x;
    if (i < n) p[i] = 0;
}

// bucket histogram of dst>>BSH (per-block LDS, one global atomic per bucket/block)
__global__ void k_bhist(const int* __restrict__ dst, int* __restrict__ bhist,
                        int E, int nbuck) {
    __shared__ int lh[MAXBUCK];
    for (int i = threadIdx.x; i < nbuck; i += TPB) lh[i] = 0;
    __syncthreads();
    for (int e = blockIdx.x * TPB + threadIdx.x; e < E; e += gridDim.x * TPB)
        atomicAdd(&lh[dst[e] >> BSH], 1);
    __syncthreads();
    for (int i = threadIdx.x; i < nbuck; i += TPB)
        if (lh[i]) atomicAdd(&bhist[i], lh[i]);
}

// single-block exclusive scan: boff (bucket offsets) + bcursor init
__global__ void k_bscan(const int* __restrict__ bhist, int* __restrict__ boff,
                        int* __restrict__ bcursor, int nbuck, int E) {
    __shared__ int sm[TPB];
    int t = threadIdx.x;
    int carry = 0;
    for (int base = 0; base < nbuck; base += TPB) {
        int i = base + t;
        int v = (i < nbuck) ? bhist[i] : 0;
        sm[t] = v;
        __syncthreads();
        for (int off = 1; off < TPB; off <<= 1) {
            int x = (t >= off) ? sm[t - off] : 0;
            __syncthreads();
            sm[t] += x;
            __syncthreads();
        }
        if (i < nbuck) { boff[i] = carry + sm[t] - v; bcursor[i] = boff[i]; }
        carry += sm[TPB - 1];
        __syncthreads();
    }
    if (t == 0) boff[nbuck] = E;
}

// partition edges into bucket-contiguous eb[] (int2: src,dst).
// per-chunk LDS histogram -> one chunk reservation atomic per bucket ->
// writes land in contiguous runs per bucket (L2 merges into full lines).
__global__ void k_part(const int* __restrict__ src, const int* __restrict__ dst,
                       int* __restrict__ bcursor, int2* __restrict__ eb,
                       int E, int nbuck) {
    __shared__ int lh[MAXBUCK];
    __shared__ int lbase[MAXBUCK];
    int t = threadIdx.x;
    int chunk0 = blockIdx.x * CH;
    int end = min(chunk0 + CH, E);
    for (int i = t; i < nbuck; i += TPB) lh[i] = 0;
    __syncthreads();
    for (int e = chunk0 + t; e < end; e += TPB)
        atomicAdd(&lh[dst[e] >> BSH], 1);
    __syncthreads();
    for (int i = t; i < nbuck; i += TPB) {
        int c = lh[i];
        lbase[i] = c ? atomicAdd(&bcursor[i], c) : 0;
        lh[i] = 0;  // reuse as local cursor
    }
    __syncthreads();
    for (int e = chunk0 + t; e < end; e += TPB) {
        int d = dst[e];
        int b = d >> BSH;
        int r = atomicAdd(&lh[b], 1);
        eb[lbase[b] + r] = make_int2(src[e], d);
    }
}

// one block per bucket: LDS counting sort over 256 local nodes ->
// csr_src (writes confined to this bucket's ~13KB window), row_start, dinv.
__global__ void k_bucket(const int2* __restrict__ eb, const int* __restrict__ boff,
                         int* __restrict__ csr_src, int* __restrict__ row_start,
                         float* __restrict__ dinv, int n, int nbuck) {
    __shared__ int lcnt[BNODES];
    __shared__ int lscan[BNODES];
    int b = blockIdx.x;
    int t = threadIdx.x;
    int node0 = b << BSH;
    int beg = boff[b], end = boff[b + 1];
    lcnt[t] = 0;
    __syncthreads();
    for (int i = beg + t; i < end; i += TPB)
        atomicAdd(&lcnt[eb[i].y & (BNODES - 1)], 1);
    __syncthreads();
    int v = lcnt[t];
    lscan[t] = v;
    __syncthreads();
    for (int off = 1; off < TPB; off <<= 1) {
        int x = (t >= off) ? lscan[t - off] : 0;
        __syncthreads();
        lscan[t] += x;
        __syncthreads();
    }
    int excl = lscan[t] - v;   // exclusive prefix within bucket
    int node = node0 + t;
    if (node < n) {
        row_start[node] = beg + excl;
        dinv[node] = rsqrtf(1.0f + (float)v);
    }
    if (b == nbuck - 1 && t == 0) row_start[n] = end;
    __syncthreads();
    lcnt[t] = excl;            // reuse as placement cursor
    __syncthreads();
    for (int i = beg + t; i < end; i += TPB) {
        int2 e = eb[i];
        int p = atomicAdd(&lcnt[e.y & (BNODES - 1)], 1);
        csr_src[beg + p] = e.x;
    }
}

// u1 = x * dinv (n x 18)
__global__ void k_scale1(const float* __restrict__ x, const float* __restrict__ dinv,
                         float* __restrict__ u1, int n) {
    int t = blockIdx.x * blockDim.x + threadIdx.x;
    if (t >= n * 18) return;
    int node = t / 18;
    u1[t] = x[t] * dinv[node];
}

// agg1[node,f] = u1[node,f] + sum_in u1[src,f], f in [0,18)
__global__ void k_agg1(const float* __restrict__ u1, const int* __restrict__ row_start,
                       const int* __restrict__ csr_src, float* __restrict__ agg1, int n) {
    int t = blockIdx.x * blockDim.x + threadIdx.x;
    if (t >= n * 18) return;
    int node = t / 18, f = t - node * 18;
    int beg = row_start[node], end = row_start[node + 1];
    float acc = u1[t];
    int i = beg;
    for (; i + 1 < end; i += 2) {
        int sa = csr_src[i];
        int sb = csr_src[i + 1];
        acc += u1[sa * 18 + f] + u1[sb * 18 + f];
    }
    if (i < end) acc += u1[csr_src[i] * 18 + f];
    agg1[t] = acc;
}

// u2[node,f2] = relu(dinv*(agg1row @ W1[:,f2]) + b1[f2]) * dinv
__global__ void k_l1(const float* __restrict__ agg1, const float* __restrict__ W1,
                     const float* __restrict__ dinv, const float* __restrict__ b1,
                     float* __restrict__ u2, int n) {
    int t = blockIdx.x * blockDim.x + threadIdx.x;
    if (t >= n * 32) return;
    int node = t >> 5, f = t & 31;
    const float* ar = agg1 + node * 18;
    float a = 0.f;
#pragma unroll
    for (int k = 0; k < 18; ++k) a = fmaf(ar[k], W1[k * 32 + f], a);
    float di = dinv[node];
    u2[t] = fmaxf(fmaf(di, a, b1[f]), 0.f) * di;
}

// agg2[node,f] = u2[node,f] + sum_in u2[src,f], f in [0,32)
__global__ void k_agg2(const float* __restrict__ u2, const int* __restrict__ row_start,
                       const int* __restrict__ csr_src, float* __restrict__ agg2, int n) {
    int t = blockIdx.x * blockDim.x + threadIdx.x;
    if (t >= n * 32) return;
    int node = t >> 5, f = t & 31;
    int beg = row_start[node], end = row_start[node + 1];
    float acc = u2[t];
    int i = beg;
    for (; i + 1 < end; i += 2) {
        int sa = csr_src[i];
        int sb = csr_src[i + 1];
        acc += u2[sa * 32 + f] + u2[sb * 32 + f];
    }
    if (i < end) acc += u2[csr_src[i] * 32 + f];
    agg2[t] = acc;
}

// per node (one wave): v = relu(dinv*(agg2row@W2)+b2); FC(64->2); log_softmax
__global__ void k_l2_out(const float* __restrict__ agg2, const float* __restrict__ W2,
                         const float* __restrict__ dinv, const float* __restrict__ b2,
                         const float* __restrict__ Wfc, const float* __restrict__ bfc,
                         float* __restrict__ out, int n) {
    int t = blockIdx.x * blockDim.x + threadIdx.x;
    int node = t >> 6, f = t & 63;
    if (node >= n) return;
    const float* ar = agg2 + node * 32;
    float a = 0.f;
#pragma unroll
    for (int k = 0; k < 32; ++k) a = fmaf(ar[k], W2[k * 64 + f], a);
    float v = fmaxf(fmaf(dinv[node], a, b2[f]), 0.f);
    float l0 = v * Wfc[f * 2 + 0];
    float l1 = v * Wfc[f * 2 + 1];
#pragma unroll
    for (int off = 32; off >= 1; off >>= 1) {
        l0 += __shfl_xor(l0, off, 64);
        l1 += __shfl_xor(l1, off, 64);
    }
    if (f == 0) {
        l0 += bfc[0];
        l1 += bfc[1];
        float m = fmaxf(l0, l1);
        float lse = m + logf(expf(l0 - m) + expf(l1 - m));
        out[node * 2 + 0] = l0 - lse;
        out[node * 2 + 1] = l1 - lse;
    }
}

extern "C" void kernel_launch(void* const* d_in, const int* in_sizes, int n_in,
                              void* d_out, int out_size, void* d_ws, size_t ws_size,
                              hipStream_t stream) {
    const float* x   = (const float*)d_in[0];
    const int*   ei  = (const int*)d_in[1];
    const float* W1  = (const float*)d_in[2];
    const float* b1  = (const float*)d_in[3];
    const float* W2  = (const float*)d_in[4];
    const float* b2  = (const float*)d_in[5];
    const float* Wfc = (const float*)d_in[6];
    const float* bfc = (const float*)d_in[7];
    float* out = (float*)d_out;

    const int n = in_sizes[0] / 18;
    const int E = in_sizes[1] / 2;
    const int* src = ei;
    const int* dst = ei + E;
    const int nbuck = (n + BNODES - 1) >> BSH;

    // ws layout (4B elems): bhist[nbuck] | boff[nbuck+1] | bcursor[nbuck]
    //  | row_start[n+1] | dinv[n] | csr_src[E] | eb[E]*2
    //  | u1[n*18] | agg1[n*18] | u2[n*32] | agg2[n*32]
    char* w = (char*)d_ws;
    int*   bhist     = (int*)w;    w += (size_t)nbuck * 4;
    int*   boff      = (int*)w;    w += (size_t)(nbuck + 1) * 4;
    int*   bcursor   = (int*)w;    w += (size_t)nbuck * 4;
    int*   row_start = (int*)w;    w += (size_t)(n + 1) * 4;
    float* dinv      = (float*)w;  w += (size_t)n * 4;
    int*   csr_src   = (int*)w;    w += (size_t)E * 4;
    int2*  eb        = (int2*)w;   w += (size_t)E * 8;
    float* u1        = (float*)w;  w += (size_t)n * 18 * 4;
    float* agg1      = (float*)w;  w += (size_t)n * 18 * 4;
    float* u2        = (float*)w;  w += (size_t)n * 32 * 4;
    float* agg2      = (float*)w;  w += (size_t)n * 32 * 4;

    auto blocks = [](long long work) { return (int)((work + TPB - 1) / TPB); };

    // ---- CSR build: bucketed counting sort ----
    k_zero<<<blocks(nbuck), TPB, 0, stream>>>(bhist, nbuck);
    k_bhist<<<256, TPB, 0, stream>>>(dst, bhist, E, nbuck);
    k_bscan<<<1, TPB, 0, stream>>>(bhist, boff, bcursor, nbuck, E);
    k_part<<<(E + CH - 1) / CH, TPB, 0, stream>>>(src, dst, bcursor, eb, E, nbuck);
    k_bucket<<<nbuck, TPB, 0, stream>>>(eb, boff, csr_src, row_start, dinv, n, nbuck);

    // ---- layer 1 ----
    k_scale1<<<blocks((long long)n * 18), TPB, 0, stream>>>(x, dinv, u1, n);
    k_agg1<<<blocks((long long)n * 18), TPB, 0, stream>>>(u1, row_start, csr_src, agg1, n);
    k_l1<<<blocks((long long)n * 32), TPB, 0, stream>>>(agg1, W1, dinv, b1, u2, n);

    // ---- layer 2 + output head ----
    k_agg2<<<blocks((long long)n * 32), TPB, 0, stream>>>(u2, row_start, csr_src, agg2, n);
    k_l2_out<<<blocks((long long)n * 64), TPB, 0, stream>>>(agg2, W2, dinv, b2, Wfc, bfc, out, n);
}

// Round 5
// 254.215 us; speedup vs baseline: 2.4985x; 1.1352x over previous
//
#include <hip/hip_runtime.h>
#include <math.h>

// GCN, aggregate-then-transform. CSR via bucketed counting sort (R4).
// R5: wave-per-node compute kernels — activation rows via wave-uniform
// (scalar) loads, weight columns register-resident, uniform loop bounds.

#define TPB 256
#define BSH 8                 // 256 nodes per bucket
#define BNODES 256
#define MAXBUCK 512
#define CH 8192               // edges per partition block
#define NPW 8                 // nodes per wave in transform kernels

__global__ void k_zero(int* __restrict__ p, int n) {
    int i = blockIdx.x * blockDim.x + threadIdx.x;
    if (i < n) p[i] = 0;
}

__global__ void k_bhist(const int* __restrict__ dst, int* __restrict__ bhist,
                        int E, int nbuck) {
    __shared__ int lh[MAXBUCK];
    for (int i = threadIdx.x; i < nbuck; i += TPB) lh[i] = 0;
    __syncthreads();
    for (int e = blockIdx.x * TPB + threadIdx.x; e < E; e += gridDim.x * TPB)
        atomicAdd(&lh[dst[e] >> BSH], 1);
    __syncthreads();
    for (int i = threadIdx.x; i < nbuck; i += TPB)
        if (lh[i]) atomicAdd(&bhist[i], lh[i]);
}

__global__ void k_bscan(const int* __restrict__ bhist, int* __restrict__ boff,
                        int* __restrict__ bcursor, int nbuck, int E) {
    __shared__ int sm[TPB];
    int t = threadIdx.x;
    int carry = 0;
    for (int base = 0; base < nbuck; base += TPB) {
        int i = base + t;
        int v = (i < nbuck) ? bhist[i] : 0;
        sm[t] = v;
        __syncthreads();
        for (int off = 1; off < TPB; off <<= 1) {
            int x = (t >= off) ? sm[t - off] : 0;
            __syncthreads();
            sm[t] += x;
            __syncthreads();
        }
        if (i < nbuck) { boff[i] = carry + sm[t] - v; bcursor[i] = boff[i]; }
        carry += sm[TPB - 1];
        __syncthreads();
    }
    if (t == 0) boff[nbuck] = E;
}

__global__ void k_part(const int* __restrict__ src, const int* __restrict__ dst,
                       int* __restrict__ bcursor, int2* __restrict__ eb,
                       int E, int nbuck) {
    __shared__ int lh[MAXBUCK];
    __shared__ int lbase[MAXBUCK];
    int t = threadIdx.x;
    int chunk0 = blockIdx.x * CH;
    int end = min(chunk0 + CH, E);
    for (int i = t; i < nbuck; i += TPB) lh[i] = 0;
    __syncthreads();
    for (int e = chunk0 + t; e < end; e += TPB)
        atomicAdd(&lh[dst[e] >> BSH], 1);
    __syncthreads();
    for (int i = t; i < nbuck; i += TPB) {
        int c = lh[i];
        lbase[i] = c ? atomicAdd(&bcursor[i], c) : 0;
        lh[i] = 0;
    }
    __syncthreads();
    for (int e = chunk0 + t; e < end; e += TPB) {
        int d = dst[e];
        int b = d >> BSH;
        int r = atomicAdd(&lh[b], 1);
        eb[lbase[b] + r] = make_int2(src[e], d);
    }
}

__global__ void k_bucket(const int2* __restrict__ eb, const int* __restrict__ boff,
                         int* __restrict__ csr_src, int* __restrict__ row_start,
                         float* __restrict__ dinv, int n, int nbuck) {
    __shared__ int lcnt[BNODES];
    __shared__ int lscan[BNODES];
    int b = blockIdx.x;
    int t = threadIdx.x;
    int node0 = b << BSH;
    int beg = boff[b], end = boff[b + 1];
    lcnt[t] = 0;
    __syncthreads();
    for (int i = beg + t; i < end; i += TPB)
        atomicAdd(&lcnt[eb[i].y & (BNODES - 1)], 1);
    __syncthreads();
    int v = lcnt[t];
    lscan[t] = v;
    __syncthreads();
    for (int off = 1; off < TPB; off <<= 1) {
        int x = (t >= off) ? lscan[t - off] : 0;
        __syncthreads();
        lscan[t] += x;
        __syncthreads();
    }
    int excl = lscan[t] - v;
    int node = node0 + t;
    if (node < n) {
        row_start[node] = beg + excl;
        dinv[node] = rsqrtf(1.0f + (float)v);
    }
    if (b == nbuck - 1 && t == 0) row_start[n] = end;
    __syncthreads();
    lcnt[t] = excl;
    __syncthreads();
    for (int i = beg + t; i < end; i += TPB) {
        int2 e = eb[i];
        int p = atomicAdd(&lcnt[e.y & (BNODES - 1)], 1);
        csr_src[beg + p] = e.x;
    }
}

// u1 = x * dinv (n x 18)
__global__ void k_scale1(const float* __restrict__ x, const float* __restrict__ dinv,
                         float* __restrict__ u1, int n) {
    int t = blockIdx.x * blockDim.x + threadIdx.x;
    if (t >= n * 18) return;
    int node = t / 18;
    u1[t] = x[t] * dinv[node];
}

// agg1: one wave per node; halves process 2 edges/iter; f in [0,18)
__global__ void k_agg1(const float* __restrict__ u1, const int* __restrict__ row_start,
                       const int* __restrict__ csr, float* __restrict__ agg1, int n) {
    int lane = threadIdx.x & 63;
    int f = lane & 31, h = lane >> 5;
    int wid = __builtin_amdgcn_readfirstlane((int)(threadIdx.x >> 6));
    int node = blockIdx.x * (TPB / 64) + wid;
    if (node >= n) return;
    bool act = f < 18;
    int beg = row_start[node], end = row_start[node + 1];
    float acc = 0.f;
    if (act && h == 0) acc = u1[(size_t)node * 18 + f];
    int i = beg;
    for (; i + 4 <= end; i += 4) {
        int e0 = csr[i], e1 = csr[i + 1], e2 = csr[i + 2], e3 = csr[i + 3];
        int ea = h ? e1 : e0;
        int eb2 = h ? e3 : e2;
        if (act) {
            acc += u1[(size_t)ea * 18 + f];
            acc += u1[(size_t)eb2 * 18 + f];
        }
    }
    for (; i < end; i += 2) {
        int e0 = csr[i];
        int e1 = (i + 1 < end) ? csr[i + 1] : e0;
        int e = h ? e1 : e0;
        if (act && (h == 0 || i + 1 < end)) acc += u1[(size_t)e * 18 + f];
    }
    acc += __shfl_xor(acc, 32, 64);
    if (act && h == 0) agg1[(size_t)node * 18 + f] = acc;
}

// l1: one wave per node (NPW nodes/wave). Row in SGPRs, W1 halves in VGPRs.
// lanes: f = lane&31 (output), h = lane>>5 (k-half: 0 -> k 0..8, 1 -> k 9..17)
__global__ void k_l1(const float* __restrict__ agg1, const float* __restrict__ W1,
                     const float* __restrict__ dinv, const float* __restrict__ b1,
                     float* __restrict__ u2, int n) {
    int lane = threadIdx.x & 63;
    int f = lane & 31, h = lane >> 5;
    int wid = __builtin_amdgcn_readfirstlane((int)(threadIdx.x >> 6));
    int wave = blockIdx.x * (TPB / 64) + wid;
    float w[9];
#pragma unroll
    for (int kk = 0; kk < 9; ++kk) w[kk] = W1[(h * 9 + kk) * 32 + f];
    float b1v = b1[f];
    int node0 = wave * NPW;
    for (int r = 0; r < NPW; ++r) {
        int node = node0 + r;
        if (node >= n) return;
        const float* rp = agg1 + (size_t)node * 18;
        float a0 = 0.f, a1 = 0.f, a2 = 0.f;
#pragma unroll
        for (int kk = 0; kk < 9; kk += 3) {
            float s0 = h ? rp[9 + kk] : rp[kk];
            float s1 = h ? rp[10 + kk] : rp[kk + 1];
            float s2 = h ? rp[11 + kk] : rp[kk + 2];
            a0 = fmaf(s0, w[kk], a0);
            a1 = fmaf(s1, w[kk + 1], a1);
            a2 = fmaf(s2, w[kk + 2], a2);
        }
        float a = a0 + a1 + a2;
        a += __shfl_xor(a, 32, 64);
        float di = dinv[node];
        if (h == 0) u2[(size_t)node * 32 + f] = fmaxf(fmaf(di, a, b1v), 0.f) * di;
    }
}

// agg2: one wave per node; halves process 2 edges/iter; f in [0,32)
__global__ void k_agg2(const float* __restrict__ u2, const int* __restrict__ row_start,
                       const int* __restrict__ csr, float* __restrict__ agg2, int n) {
    int lane = threadIdx.x & 63;
    int f = lane & 31, h = lane >> 5;
    int wid = __builtin_amdgcn_readfirstlane((int)(threadIdx.x >> 6));
    int node = blockIdx.x * (TPB / 64) + wid;
    if (node >= n) return;
    int beg = row_start[node], end = row_start[node + 1];
    float acc = (h == 0) ? u2[(size_t)node * 32 + f] : 0.f;
    int i = beg;
    for (; i + 4 <= end; i += 4) {
        int e0 = csr[i], e1 = csr[i + 1], e2 = csr[i + 2], e3 = csr[i + 3];
        int ea = h ? e1 : e0;
        int eb2 = h ? e3 : e2;
        acc += u2[(size_t)ea * 32 + f];
        acc += u2[(size_t)eb2 * 32 + f];
    }
    for (; i < end; i += 2) {
        int e0 = csr[i];
        int e1 = (i + 1 < end) ? csr[i + 1] : e0;
        int e = h ? e1 : e0;
        float v = u2[(size_t)e * 32 + f];
        if (h && i + 1 >= end) v = 0.f;
        acc += v;
    }
    acc += __shfl_xor(acc, 32, 64);
    if (h == 0) agg2[(size_t)node * 32 + f] = acc;
}

// l2 + head: one wave per node (NPW nodes/wave). Row (32) in SGPRs,
// W2 column `lane` in 32 VGPRs; FC(64->2) via shfl butterfly; log_softmax.
__global__ void k_l2_out(const float* __restrict__ agg2, const float* __restrict__ W2,
                         const float* __restrict__ dinv, const float* __restrict__ b2,
                         const float* __restrict__ Wfc, const float* __restrict__ bfc,
                         float* __restrict__ out, int n) {
    int lane = threadIdx.x & 63;
    int wid = __builtin_amdgcn_readfirstlane((int)(threadIdx.x >> 6));
    int wave = blockIdx.x * (TPB / 64) + wid;
    float w[32];
#pragma unroll
    for (int k = 0; k < 32; ++k) w[k] = W2[k * 64 + lane];
    float b2v = b2[lane];
    float wf0 = Wfc[lane * 2 + 0], wf1 = Wfc[lane * 2 + 1];
    float bf0 = bfc[0], bf1 = bfc[1];
    int node0 = wave * NPW;
    for (int r = 0; r < NPW; ++r) {
        int node = node0 + r;
        if (node >= n) return;
        const float* rp = agg2 + (size_t)node * 32;
        float a0 = 0.f, a1 = 0.f, a2 = 0.f, a3 = 0.f;
#pragma unroll
        for (int k = 0; k < 32; k += 4) {
            a0 = fmaf(rp[k],     w[k],     a0);
            a1 = fmaf(rp[k + 1], w[k + 1], a1);
            a2 = fmaf(rp[k + 2], w[k + 2], a2);
            a3 = fmaf(rp[k + 3], w[k + 3], a3);
        }
        float a = (a0 + a1) + (a2 + a3);
        float v = fmaxf(fmaf(dinv[node], a, b2v), 0.f);
        float l0 = v * wf0;
        float l1 = v * wf1;
#pragma unroll
        for (int off = 32; off >= 1; off >>= 1) {
            l0 += __shfl_xor(l0, off, 64);
            l1 += __shfl_xor(l1, off, 64);
        }
        if (lane == 0) {
            l0 += bf0;
            l1 += bf1;
            float m = fmaxf(l0, l1);
            float lse = m + logf(expf(l0 - m) + expf(l1 - m));
            out[node * 2 + 0] = l0 - lse;
            out[node * 2 + 1] = l1 - lse;
        }
    }
}

extern "C" void kernel_launch(void* const* d_in, const int* in_sizes, int n_in,
                              void* d_out, int out_size, void* d_ws, size_t ws_size,
                              hipStream_t stream) {
    const float* x   = (const float*)d_in[0];
    const int*   ei  = (const int*)d_in[1];
    const float* W1  = (const float*)d_in[2];
    const float* b1  = (const float*)d_in[3];
    const float* W2  = (const float*)d_in[4];
    const float* b2  = (const float*)d_in[5];
    const float* Wfc = (const float*)d_in[6];
    const float* bfc = (const float*)d_in[7];
    float* out = (float*)d_out;

    const int n = in_sizes[0] / 18;
    const int E = in_sizes[1] / 2;
    const int* src = ei;
    const int* dst = ei + E;
    const int nbuck = (n + BNODES - 1) >> BSH;

    // ws layout (4B elems): bhist[nbuck] | boff[nbuck+1] | bcursor[nbuck]
    //  | row_start[n+1] | dinv[n] | csr_src[E] | eb[E]*2
    //  | u1[n*18] | agg1[n*18] | u2[n*32] | agg2[n*32]
    char* w = (char*)d_ws;
    int*   bhist     = (int*)w;    w += (size_t)nbuck * 4;
    int*   boff      = (int*)w;    w += (size_t)(nbuck + 1) * 4;
    int*   bcursor   = (int*)w;    w += (size_t)nbuck * 4;
    int*   row_start = (int*)w;    w += (size_t)(n + 1) * 4;
    float* dinv      = (float*)w;  w += (size_t)n * 4;
    int*   csr_src   = (int*)w;    w += (size_t)E * 4;
    int2*  eb        = (int2*)w;   w += (size_t)E * 8;
    float* u1        = (float*)w;  w += (size_t)n * 18 * 4;
    float* agg1      = (float*)w;  w += (size_t)n * 18 * 4;
    float* u2        = (float*)w;  w += (size_t)n * 32 * 4;
    float* agg2      = (float*)w;  w += (size_t)n * 32 * 4;

    auto blocks = [](long long work) { return (int)((work + TPB - 1) / TPB); };

    // ---- CSR build: bucketed counting sort ----
    k_zero<<<blocks(nbuck), TPB, 0, stream>>>(bhist, nbuck);
    k_bhist<<<256, TPB, 0, stream>>>(dst, bhist, E, nbuck);
    k_bscan<<<1, TPB, 0, stream>>>(bhist, boff, bcursor, nbuck, E);
    k_part<<<(E + CH - 1) / CH, TPB, 0, stream>>>(src, dst, bcursor, eb, E, nbuck);
    k_bucket<<<nbuck, TPB, 0, stream>>>(eb, boff, csr_src, row_start, dinv, n, nbuck);

    const int wavesT = (n + NPW - 1) / NPW;            // transform kernels
    const int blocksT = (wavesT + (TPB / 64) - 1) / (TPB / 64);
    const int blocksA = (n + (TPB / 64) - 1) / (TPB / 64);  // agg kernels (1 node/wave)

    // ---- layer 1 ----
    k_scale1<<<blocks((long long)n * 18), TPB, 0, stream>>>(x, dinv, u1, n);
    k_agg1<<<blocksA, TPB, 0, stream>>>(u1, row_start, csr_src, agg1, n);
    k_l1<<<blocksT, TPB, 0, stream>>>(agg1, W1, dinv, b1, u2, n);

    // ---- layer 2 + output head ----
    k_agg2<<<blocksA, TPB, 0, stream>>>(u2, row_start, csr_src, agg2, n);
    k_l2_out<<<blocksT, TPB, 0, stream>>>(agg2, W2, dinv, b2, Wfc, bfc, out, n);
}